// Round 2
// baseline (750.696 us; speedup 1.0000x reference)
//
#include <hip/hip_runtime.h>

#define NCOPY 8  // one vd copy per XCD

// clang-native vector types: __builtin_nontemporal_* rejects HIP_vector_type wrappers.
typedef int          nt_int4  __attribute__((ext_vector_type(4)));
typedef unsigned int nt_uint4 __attribute__((ext_vector_type(4)));

// ---------------- fast path ----------------

__global__ __launch_bounds__(256) void zero_ws_kernel(uint4* __restrict__ p, int n4) {
    int i = blockIdx.x * blockDim.x + threadIdx.x;
    if (i < n4) p[i] = make_uint4(0u, 0u, 0u, 0u);
}

// Pad 12B-strided verts to 16B float4 so gathers are one aligned dwordx4.
__global__ __launch_bounds__(256) void pad_verts_kernel(const float* __restrict__ verts,
                                                        float4* __restrict__ verts4, int V) {
    int i = blockIdx.x * blockDim.x + threadIdx.x;
    if (i < V) {
        const float* p = verts + (size_t)i * 3;
        verts4[i] = make_float4(p[0], p[1], p[2], 0.f);
    }
}

__global__ __launch_bounds__(256) void tet_kernel(
    const float4* __restrict__ verts4,
    const int*   __restrict__ indices,   // 4*T ints
    const float* __restrict__ density,
    float* __restrict__ out_area,
    float* __restrict__ out_alpha,
    unsigned int* __restrict__ vd_ws,   // NCOPY x V uints
    int T, int V)
{
    int i = blockIdx.x * blockDim.x + threadIdx.x;
    if (i >= T) return;

    // Physical XCD id: atomics into this XCD's private copy stay cached in the
    // local TCC (workgroup scope => no sc1 L2-bypass), instead of 32B RMWs at
    // the device coherence point.
    unsigned int xcc;
    asm("s_getreg_b32 %0, hwreg(HW_REG_XCC_ID)" : "=s"(xcc));
    unsigned int* vd = vd_ws + (size_t)(xcc & (NCOPY - 1)) * (unsigned)V;

    // Pure streams: non-temporal so they don't evict vd / vertex lines in L2.
    nt_int4 idx = __builtin_nontemporal_load((const nt_int4*)indices + i);
    float d     = __builtin_nontemporal_load(&density[i]);

    float4 v0 = verts4[idx.x];
    float4 v1 = verts4[idx.y];
    float4 v2 = verts4[idx.z];
    float4 v3 = verts4[idx.w];

    float e1x = v1.x - v0.x, e1y = v1.y - v0.y, e1z = v1.z - v0.z;
    float e2x = v2.x - v0.x, e2y = v2.y - v0.y, e2z = v2.z - v0.z;
    float e3x = v3.x - v0.x, e3y = v3.y - v0.y, e3z = v3.z - v0.z;

    float det = e1x * (e2y * e3z - e2z * e3y)
              - e1y * (e2x * e3z - e2z * e3x)
              + e1z * (e2x * e3y - e2y * e3x);
    __builtin_nontemporal_store(fabsf(det) * (1.0f / 6.0f), &out_area[i]);

    float q01 = e1x * e1x + e1y * e1y + e1z * e1z;
    float q02 = e2x * e2x + e2y * e2y + e2z * e2z;
    float q03 = e3x * e3x + e3y * e3y + e3z * e3z;
    float ax, ay, az;
    ax = v1.x - v2.x; ay = v1.y - v2.y; az = v1.z - v2.z;
    float q12 = ax * ax + ay * ay + az * az;
    ax = v1.x - v3.x; ay = v1.y - v3.y; az = v1.z - v3.z;
    float q13 = ax * ax + ay * ay + az * az;
    ax = v2.x - v3.x; ay = v2.y - v3.y; az = v2.z - v3.z;
    float q23 = ax * ax + ay * ay + az * az;

    float mn = fminf(fminf(fminf(q01, q02), fminf(q03, q12)), fminf(q13, q23));
    float el = sqrtf(mn);
    __builtin_nontemporal_store(1.0f - expf(-d * el), &out_alpha[i]);

    // Positive floats compare identically as unsigned ints.
    unsigned int db = __float_as_uint(d);
    __hip_atomic_fetch_max(vd + idx.x, db, __ATOMIC_RELAXED, __HIP_MEMORY_SCOPE_WORKGROUP);
    __hip_atomic_fetch_max(vd + idx.y, db, __ATOMIC_RELAXED, __HIP_MEMORY_SCOPE_WORKGROUP);
    __hip_atomic_fetch_max(vd + idx.z, db, __ATOMIC_RELAXED, __HIP_MEMORY_SCOPE_WORKGROUP);
    __hip_atomic_fetch_max(vd + idx.w, db, __ATOMIC_RELAXED, __HIP_MEMORY_SCOPE_WORKGROUP);
}

// vd[v] = max over the NCOPY per-XCD partial copies (uint compare == float max).
__global__ __launch_bounds__(256) void reduce_vd_kernel(const nt_uint4* __restrict__ ws,
                                                        nt_uint4* __restrict__ out, int V4) {
    int i = blockIdx.x * blockDim.x + threadIdx.x;
    if (i >= V4) return;
    nt_uint4 m = ws[i];
#pragma unroll
    for (int c = 1; c < NCOPY; ++c) {
        nt_uint4 t = ws[(size_t)c * V4 + i];
        m.x = m.x > t.x ? m.x : t.x;
        m.y = m.y > t.y ? m.y : t.y;
        m.z = m.z > t.z ? m.z : t.z;
        m.w = m.w > t.w ? m.w : t.w;
    }
    __builtin_nontemporal_store(m, out + i);
}

// ---------------- fallback path (previous verified kernel) ----------------

__global__ __launch_bounds__(256) void zero_vd_kernel(float4* __restrict__ vd4, int n4) {
    int i = blockIdx.x * blockDim.x + threadIdx.x;
    if (i < n4) vd4[i] = make_float4(0.f, 0.f, 0.f, 0.f);
}

__global__ __launch_bounds__(256) void tet_kernel_fb(
    const float* __restrict__ verts,
    const int4*  __restrict__ indices,
    const float* __restrict__ density,
    float* __restrict__ out_area,
    float* __restrict__ out_alpha,
    unsigned int* __restrict__ vd,
    int T)
{
    int i = blockIdx.x * blockDim.x + threadIdx.x;
    if (i >= T) return;

    int4 idx = indices[i];
    float d = density[i];

    const float* p;
    p = verts + idx.x * 3; float v0x = p[0], v0y = p[1], v0z = p[2];
    p = verts + idx.y * 3; float v1x = p[0], v1y = p[1], v1z = p[2];
    p = verts + idx.z * 3; float v2x = p[0], v2y = p[1], v2z = p[2];
    p = verts + idx.w * 3; float v3x = p[0], v3y = p[1], v3z = p[2];

    float e1x = v1x - v0x, e1y = v1y - v0y, e1z = v1z - v0z;
    float e2x = v2x - v0x, e2y = v2y - v0y, e2z = v2z - v0z;
    float e3x = v3x - v0x, e3y = v3y - v0y, e3z = v3z - v0z;

    float det = e1x * (e2y * e3z - e2z * e3y)
              - e1y * (e2x * e3z - e2z * e3x)
              + e1z * (e2x * e3y - e2y * e3x);
    out_area[i] = fabsf(det) * (1.0f / 6.0f);

    float q01 = e1x * e1x + e1y * e1y + e1z * e1z;
    float q02 = e2x * e2x + e2y * e2y + e2z * e2z;
    float q03 = e3x * e3x + e3y * e3y + e3z * e3z;
    float ax, ay, az;
    ax = v1x - v2x; ay = v1y - v2y; az = v1z - v2z;
    float q12 = ax * ax + ay * ay + az * az;
    ax = v1x - v3x; ay = v1y - v3y; az = v1z - v3z;
    float q13 = ax * ax + ay * ay + az * az;
    ax = v2x - v3x; ay = v2y - v3y; az = v2z - v3z;
    float q23 = ax * ax + ay * ay + az * az;

    float mn = fminf(fminf(fminf(q01, q02), fminf(q03, q12)), fminf(q13, q23));
    float el = sqrtf(mn);
    out_alpha[i] = 1.0f - expf(-d * el);

    unsigned int db = __float_as_uint(d);
    atomicMax(vd + idx.x, db);
    atomicMax(vd + idx.y, db);
    atomicMax(vd + idx.z, db);
    atomicMax(vd + idx.w, db);
}

// ---------------- launch ----------------

extern "C" void kernel_launch(void* const* d_in, const int* in_sizes, int n_in,
                              void* d_out, int out_size, void* d_ws, size_t ws_size,
                              hipStream_t stream) {
    const float* verts   = (const float*)d_in[0];
    const int*   indices = (const int*)d_in[1];
    const float* density = (const float*)d_in[2];
    int T = in_sizes[2];        // 4,000,000 tets
    int V = in_sizes[0] / 3;    // 1,000,000 vertices

    float* out       = (float*)d_out;
    float* out_area  = out;
    float* out_alpha = out + (size_t)T;
    unsigned int* vd = (unsigned int*)(out + 2 * (size_t)T);

    const int block = 256;
    size_t need = (size_t)NCOPY * V * sizeof(unsigned int) + (size_t)V * sizeof(float4);

    if (d_ws && ws_size >= need && (V % 4) == 0) {
        unsigned int* vd_ws = (unsigned int*)d_ws;
        float4* verts4 = (float4*)((char*)d_ws + (size_t)NCOPY * V * sizeof(unsigned int));

        int n4z = NCOPY * (V / 4);
        zero_ws_kernel<<<(n4z + block - 1) / block, block, 0, stream>>>((uint4*)vd_ws, n4z);
        pad_verts_kernel<<<(V + block - 1) / block, block, 0, stream>>>(verts, verts4, V);

        tet_kernel<<<(T + block - 1) / block, block, 0, stream>>>(
            verts4, indices, density, out_area, out_alpha, vd_ws, T, V);

        int V4 = V / 4;
        reduce_vd_kernel<<<(V4 + block - 1) / block, block, 0, stream>>>(
            (const nt_uint4*)vd_ws, (nt_uint4*)vd, V4);
    } else {
        int n4 = V / 4;
        zero_vd_kernel<<<(n4 + block - 1) / block, block, 0, stream>>>((float4*)vd, n4);
        tet_kernel_fb<<<(T + block - 1) / block, block, 0, stream>>>(
            verts, (const int4*)indices, density, out_area, out_alpha, vd, T);
    }
}

// Round 3
// 643.652 us; speedup vs baseline: 1.1663x; 1.1663x over previous
//
#include <hip/hip_runtime.h>

// clang-native vector types: __builtin_nontemporal_* rejects HIP_vector_type wrappers.
typedef int nt_int4 __attribute__((ext_vector_type(4)));

// Zero the vert_density region (harness poisons d_out with 0xAA each launch).
__global__ __launch_bounds__(256) void zero_vd_kernel(float4* __restrict__ vd4, int n4) {
    int i = blockIdx.x * blockDim.x + threadIdx.x;
    if (i < n4) vd4[i] = make_float4(0.f, 0.f, 0.f, 0.f);
}

// Pad 12B-strided verts to 16B float4 so gathers are one aligned dwordx4.
__global__ __launch_bounds__(256) void pad_verts_kernel(const float* __restrict__ verts,
                                                        float4* __restrict__ verts4, int V) {
    int i = blockIdx.x * blockDim.x + threadIdx.x;
    if (i < V) {
        const float* p = verts + (size_t)i * 3;
        verts4[i] = make_float4(p[0], p[1], p[2], 0.f);
    }
}

__global__ __launch_bounds__(256) void tet_kernel(
    const float4* __restrict__ verts4,
    const int*   __restrict__ indices,   // 4*T ints
    const float* __restrict__ density,
    float* __restrict__ out_area,
    float* __restrict__ out_alpha,
    unsigned int* __restrict__ vd,
    int T)
{
    int i = blockIdx.x * blockDim.x + threadIdx.x;
    if (i >= T) return;

    // Pure streams: non-temporal so they don't evict vd / vertex lines in L2.
    nt_int4 idx = __builtin_nontemporal_load((const nt_int4*)indices + i);
    float d     = __builtin_nontemporal_load(&density[i]);
    unsigned int db = __float_as_uint(d);  // positive floats compare as uints

    // Filter reads: vd is monotone non-decreasing, so a stale (cached) value is
    // always <= the true value -> skipping only when db <= cur is always safe.
    // 4 MB table stays cache-resident; this converts ~16M atomic RMWs into
    // ~16M cached reads + only the record-breaking atomics (~H_16 per vertex).
    unsigned int c0 = vd[idx.x];
    unsigned int c1 = vd[idx.y];
    unsigned int c2 = vd[idx.z];
    unsigned int c3 = vd[idx.w];

    float4 v0 = verts4[idx.x];
    float4 v1 = verts4[idx.y];
    float4 v2 = verts4[idx.z];
    float4 v3 = verts4[idx.w];

    float e1x = v1.x - v0.x, e1y = v1.y - v0.y, e1z = v1.z - v0.z;
    float e2x = v2.x - v0.x, e2y = v2.y - v0.y, e2z = v2.z - v0.z;
    float e3x = v3.x - v0.x, e3y = v3.y - v0.y, e3z = v3.z - v0.z;

    float det = e1x * (e2y * e3z - e2z * e3y)
              - e1y * (e2x * e3z - e2z * e3x)
              + e1z * (e2x * e3y - e2y * e3x);
    __builtin_nontemporal_store(fabsf(det) * (1.0f / 6.0f), &out_area[i]);

    float q01 = e1x * e1x + e1y * e1y + e1z * e1z;
    float q02 = e2x * e2x + e2y * e2y + e2z * e2z;
    float q03 = e3x * e3x + e3y * e3y + e3z * e3z;
    float ax, ay, az;
    ax = v1.x - v2.x; ay = v1.y - v2.y; az = v1.z - v2.z;
    float q12 = ax * ax + ay * ay + az * az;
    ax = v1.x - v3.x; ay = v1.y - v3.y; az = v1.z - v3.z;
    float q13 = ax * ax + ay * ay + az * az;
    ax = v2.x - v3.x; ay = v2.y - v3.y; az = v2.z - v3.z;
    float q23 = ax * ax + ay * ay + az * az;

    float mn = fminf(fminf(fminf(q01, q02), fminf(q03, q12)), fminf(q13, q23));
    float el = sqrtf(mn);
    __builtin_nontemporal_store(1.0f - expf(-d * el), &out_alpha[i]);

    if (db > c0) atomicMax(vd + idx.x, db);
    if (db > c1) atomicMax(vd + idx.y, db);
    if (db > c2) atomicMax(vd + idx.z, db);
    if (db > c3) atomicMax(vd + idx.w, db);
}

// ---------------- fallback path (round-0 verified kernel) ----------------

__global__ __launch_bounds__(256) void tet_kernel_fb(
    const float* __restrict__ verts,
    const int4*  __restrict__ indices,
    const float* __restrict__ density,
    float* __restrict__ out_area,
    float* __restrict__ out_alpha,
    unsigned int* __restrict__ vd,
    int T)
{
    int i = blockIdx.x * blockDim.x + threadIdx.x;
    if (i >= T) return;

    int4 idx = indices[i];
    float d = density[i];

    const float* p;
    p = verts + idx.x * 3; float v0x = p[0], v0y = p[1], v0z = p[2];
    p = verts + idx.y * 3; float v1x = p[0], v1y = p[1], v1z = p[2];
    p = verts + idx.z * 3; float v2x = p[0], v2y = p[1], v2z = p[2];
    p = verts + idx.w * 3; float v3x = p[0], v3y = p[1], v3z = p[2];

    float e1x = v1x - v0x, e1y = v1y - v0y, e1z = v1z - v0z;
    float e2x = v2x - v0x, e2y = v2y - v0y, e2z = v2z - v0z;
    float e3x = v3x - v0x, e3y = v3y - v0y, e3z = v3z - v0z;

    float det = e1x * (e2y * e3z - e2z * e3y)
              - e1y * (e2x * e3z - e2z * e3x)
              + e1z * (e2x * e3y - e2y * e3x);
    out_area[i] = fabsf(det) * (1.0f / 6.0f);

    float q01 = e1x * e1x + e1y * e1y + e1z * e1z;
    float q02 = e2x * e2x + e2y * e2y + e2z * e2z;
    float q03 = e3x * e3x + e3y * e3y + e3z * e3z;
    float ax, ay, az;
    ax = v1x - v2x; ay = v1y - v2y; az = v1z - v2z;
    float q12 = ax * ax + ay * ay + az * az;
    ax = v1x - v3x; ay = v1y - v3y; az = v1z - v3z;
    float q13 = ax * ax + ay * ay + az * az;
    ax = v2x - v3x; ay = v2y - v3y; az = v2z - v3z;
    float q23 = ax * ax + ay * ay + az * az;

    float mn = fminf(fminf(fminf(q01, q02), fminf(q03, q12)), fminf(q13, q23));
    float el = sqrtf(mn);
    out_alpha[i] = 1.0f - expf(-d * el);

    unsigned int db = __float_as_uint(d);
    atomicMax(vd + idx.x, db);
    atomicMax(vd + idx.y, db);
    atomicMax(vd + idx.z, db);
    atomicMax(vd + idx.w, db);
}

// ---------------- launch ----------------

extern "C" void kernel_launch(void* const* d_in, const int* in_sizes, int n_in,
                              void* d_out, int out_size, void* d_ws, size_t ws_size,
                              hipStream_t stream) {
    const float* verts   = (const float*)d_in[0];
    const int*   indices = (const int*)d_in[1];
    const float* density = (const float*)d_in[2];
    int T = in_sizes[2];        // 4,000,000 tets
    int V = in_sizes[0] / 3;    // 1,000,000 vertices

    float* out       = (float*)d_out;
    float* out_area  = out;
    float* out_alpha = out + (size_t)T;
    unsigned int* vd = (unsigned int*)(out + 2 * (size_t)T);

    const int block = 256;

    // Zero vert_density region first (same stream -> ordered before reads/atomics).
    int n4 = V / 4;
    zero_vd_kernel<<<(n4 + block - 1) / block, block, 0, stream>>>((float4*)vd, n4);

    size_t need = (size_t)V * sizeof(float4);
    if (d_ws && ws_size >= need && (V % 4) == 0) {
        float4* verts4 = (float4*)d_ws;
        pad_verts_kernel<<<(V + block - 1) / block, block, 0, stream>>>(verts, verts4, V);
        tet_kernel<<<(T + block - 1) / block, block, 0, stream>>>(
            verts4, indices, density, out_area, out_alpha, vd, T);
    } else {
        tet_kernel_fb<<<(T + block - 1) / block, block, 0, stream>>>(
            verts, (const int4*)indices, density, out_area, out_alpha, vd, T);
    }
}

// Round 4
// 541.096 us; speedup vs baseline: 1.3874x; 1.1895x over previous
//
#include <hip/hip_runtime.h>

// clang-native vector types: __builtin_nontemporal_* rejects HIP_vector_type wrappers.
typedef int nt_int4 __attribute__((ext_vector_type(4)));

#define NB     256        // vertex buckets
#define VSHIFT 12         // 4096 verts per bucket -> 16 KB LDS table
#define BMASK  ((1 << VSHIFT) - 1)
#define BCAP   65536      // pairs per bucket capacity (mean 62.5K + 12 sigma)
#define KT     16         // tets per thread in bin_kernel

// Zero vd region (harness poisons d_out) and the global bucket counters.
__global__ __launch_bounds__(256) void zero_kernel(uint4* __restrict__ vd4, int n4,
                                                   unsigned* __restrict__ gcnt) {
    int i = blockIdx.x * blockDim.x + threadIdx.x;
    if (i < n4) vd4[i] = make_uint4(0u, 0u, 0u, 0u);
    if (gcnt && i < NB) gcnt[i] = 0u;
}

// Pad 12B-strided verts to 16B float4 so gathers are one aligned dwordx4.
__global__ __launch_bounds__(256) void pad_verts_kernel(const float* __restrict__ verts,
                                                        float4* __restrict__ verts4, int V) {
    int i = blockIdx.x * blockDim.x + threadIdx.x;
    if (i < V) {
        const float* p = verts + (size_t)i * 3;
        verts4[i] = make_float4(p[0], p[1], p[2], 0.f);
    }
}

// ---- pure geometry: no vd state touched (that was 1+ GB of filter-read misses) ----
__global__ __launch_bounds__(256) void geom_kernel_v4(
    const float4* __restrict__ verts4,
    const int*   __restrict__ indices,
    const float* __restrict__ density,
    float* __restrict__ out_area,
    float* __restrict__ out_alpha,
    int T)
{
    int i = blockIdx.x * blockDim.x + threadIdx.x;
    if (i >= T) return;

    nt_int4 idx = __builtin_nontemporal_load((const nt_int4*)indices + i);
    float d     = __builtin_nontemporal_load(&density[i]);

    float4 v0 = verts4[idx.x];
    float4 v1 = verts4[idx.y];
    float4 v2 = verts4[idx.z];
    float4 v3 = verts4[idx.w];

    float e1x = v1.x - v0.x, e1y = v1.y - v0.y, e1z = v1.z - v0.z;
    float e2x = v2.x - v0.x, e2y = v2.y - v0.y, e2z = v2.z - v0.z;
    float e3x = v3.x - v0.x, e3y = v3.y - v0.y, e3z = v3.z - v0.z;

    float det = e1x * (e2y * e3z - e2z * e3y)
              - e1y * (e2x * e3z - e2z * e3x)
              + e1z * (e2x * e3y - e2y * e3x);
    __builtin_nontemporal_store(fabsf(det) * (1.0f / 6.0f), &out_area[i]);

    float q01 = e1x * e1x + e1y * e1y + e1z * e1z;
    float q02 = e2x * e2x + e2y * e2y + e2z * e2z;
    float q03 = e3x * e3x + e3y * e3y + e3z * e3z;
    float ax, ay, az;
    ax = v1.x - v2.x; ay = v1.y - v2.y; az = v1.z - v2.z;
    float q12 = ax * ax + ay * ay + az * az;
    ax = v1.x - v3.x; ay = v1.y - v3.y; az = v1.z - v3.z;
    float q13 = ax * ax + ay * ay + az * az;
    ax = v2.x - v3.x; ay = v2.y - v3.y; az = v2.z - v3.z;
    float q23 = ax * ax + ay * ay + az * az;

    float mn = fminf(fminf(fminf(q01, q02), fminf(q03, q12)), fminf(q13, q23));
    float el = sqrtf(mn);
    __builtin_nontemporal_store(1.0f - expf(-d * el), &out_alpha[i]);
}

// Raw-verts variant (used when ws can't hold verts4 too).
__global__ __launch_bounds__(256) void geom_kernel_raw(
    const float* __restrict__ verts,
    const int*   __restrict__ indices,
    const float* __restrict__ density,
    float* __restrict__ out_area,
    float* __restrict__ out_alpha,
    int T)
{
    int i = blockIdx.x * blockDim.x + threadIdx.x;
    if (i >= T) return;

    nt_int4 idx = __builtin_nontemporal_load((const nt_int4*)indices + i);
    float d     = __builtin_nontemporal_load(&density[i]);

    const float* p;
    p = verts + (size_t)idx.x * 3; float v0x = p[0], v0y = p[1], v0z = p[2];
    p = verts + (size_t)idx.y * 3; float v1x = p[0], v1y = p[1], v1z = p[2];
    p = verts + (size_t)idx.z * 3; float v2x = p[0], v2y = p[1], v2z = p[2];
    p = verts + (size_t)idx.w * 3; float v3x = p[0], v3y = p[1], v3z = p[2];

    float e1x = v1x - v0x, e1y = v1y - v0y, e1z = v1z - v0z;
    float e2x = v2x - v0x, e2y = v2y - v0y, e2z = v2z - v0z;
    float e3x = v3x - v0x, e3y = v3y - v0y, e3z = v3z - v0z;

    float det = e1x * (e2y * e3z - e2z * e3y)
              - e1y * (e2x * e3z - e2z * e3x)
              + e1z * (e2x * e3y - e2y * e3x);
    __builtin_nontemporal_store(fabsf(det) * (1.0f / 6.0f), &out_area[i]);

    float q01 = e1x * e1x + e1y * e1y + e1z * e1z;
    float q02 = e2x * e2x + e2y * e2y + e2z * e2z;
    float q03 = e3x * e3x + e3y * e3y + e3z * e3z;
    float ax, ay, az;
    ax = v1x - v2x; ay = v1y - v2y; az = v1z - v2z;
    float q12 = ax * ax + ay * ay + az * az;
    ax = v1x - v3x; ay = v1y - v3y; az = v1z - v3z;
    float q13 = ax * ax + ay * ay + az * az;
    ax = v2x - v3x; ay = v2y - v3y; az = v2z - v3z;
    float q23 = ax * ax + ay * ay + az * az;

    float mn = fminf(fminf(fminf(q01, q02), fminf(q03, q12)), fminf(q13, q23));
    float el = sqrtf(mn);
    __builtin_nontemporal_store(1.0f - expf(-d * el), &out_alpha[i]);
}

// ---- bucket-scatter: counting-sort (v,d) pairs into NB vertex-range buckets ----
__global__ __launch_bounds__(256) void bin_kernel(
    const int4*  __restrict__ idx4,
    const float* __restrict__ dens,
    uint2*       __restrict__ pairs,   // NB x BCAP
    unsigned*    __restrict__ gcnt,    // NB
    unsigned*    __restrict__ vd,      // overflow fallback target (zeroed)
    int T)
{
    __shared__ unsigned s_cnt[NB];
    __shared__ unsigned s_base[NB];
    int tid  = threadIdx.x;
    int base = blockIdx.x * (256 * KT);

    for (int b = tid; b < NB; b += 256) s_cnt[b] = 0u;
    __syncthreads();

    // phase 1: count (idx loads stay L2-hot for phase 3)
#pragma unroll
    for (int k = 0; k < KT; ++k) {
        int i = base + k * 256 + tid;
        if (i < T) {
            int4 q = idx4[i];
            atomicAdd(&s_cnt[(unsigned)q.x >> VSHIFT], 1u);
            atomicAdd(&s_cnt[(unsigned)q.y >> VSHIFT], 1u);
            atomicAdd(&s_cnt[(unsigned)q.z >> VSHIFT], 1u);
            atomicAdd(&s_cnt[(unsigned)q.w >> VSHIFT], 1u);
        }
    }
    __syncthreads();

    // phase 2: one global bump per bucket per block; reset local counters for ranking
    for (int b = tid; b < NB; b += 256) {
        s_base[b] = atomicAdd(&gcnt[b], s_cnt[b]);
        s_cnt[b]  = 0u;
    }
    __syncthreads();

    // phase 3: rank + write (coalescing: each block owns a contiguous segment per bucket)
#pragma unroll
    for (int k = 0; k < KT; ++k) {
        int i = base + k * 256 + tid;
        if (i < T) {
            int4 q = idx4[i];
            unsigned db = __float_as_uint(dens[i]);
            int vv[4] = { q.x, q.y, q.z, q.w };
#pragma unroll
            for (int j = 0; j < 4; ++j) {
                unsigned v = (unsigned)vv[j];
                unsigned b = v >> VSHIFT;
                unsigned r = atomicAdd(&s_cnt[b], 1u) + s_base[b];
                if (r < BCAP) pairs[(size_t)b * BCAP + r] = make_uint2(v, db);
                else          atomicMax(vd + v, db);   // astronomically rare; correct
            }
        }
    }
}

// ---- per-bucket max in LDS: zero global atomics ----
__global__ __launch_bounds__(1024) void bucket_max_kernel(
    const uint2*    __restrict__ pairs,
    const unsigned* __restrict__ gcnt,
    unsigned*       __restrict__ vd,
    int V)
{
    __shared__ unsigned tbl[1 << VSHIFT];
    int b   = blockIdx.x;
    int tid = threadIdx.x;

    for (int j = tid; j < (1 << VSHIFT); j += 1024) tbl[j] = 0u;
    __syncthreads();

    unsigned cnt = gcnt[b];
    if (cnt > BCAP) cnt = BCAP;
    const uint2* p = pairs + (size_t)b * BCAP;
    for (unsigned i = tid; i < cnt; i += 1024) {
        uint2 e = p[i];
        atomicMax(&tbl[e.x & BMASK], e.y);   // ds_max_u32: on-chip, free
    }
    __syncthreads();

    int vbase = b << VSHIFT;
    for (int j = tid; j < (1 << VSHIFT); j += 1024) {
        int v = vbase + j;
        if (v < V) {
            unsigned cur = vd[v];            // merge overflow-fallback atomics (vd zeroed)
            unsigned t   = tbl[j];
            vd[v] = cur > t ? cur : t;
        }
    }
}

// ---------------- tier-3: round-3 verified kernel (read-filtered atomics) ----------------
__global__ __launch_bounds__(256) void tet_kernel_filter(
    const float4* __restrict__ verts4,
    const int*   __restrict__ indices,
    const float* __restrict__ density,
    float* __restrict__ out_area,
    float* __restrict__ out_alpha,
    unsigned int* __restrict__ vd,
    int T)
{
    int i = blockIdx.x * blockDim.x + threadIdx.x;
    if (i >= T) return;

    nt_int4 idx = __builtin_nontemporal_load((const nt_int4*)indices + i);
    float d     = __builtin_nontemporal_load(&density[i]);
    unsigned int db = __float_as_uint(d);

    unsigned int c0 = vd[idx.x];
    unsigned int c1 = vd[idx.y];
    unsigned int c2 = vd[idx.z];
    unsigned int c3 = vd[idx.w];

    float4 v0 = verts4[idx.x];
    float4 v1 = verts4[idx.y];
    float4 v2 = verts4[idx.z];
    float4 v3 = verts4[idx.w];

    float e1x = v1.x - v0.x, e1y = v1.y - v0.y, e1z = v1.z - v0.z;
    float e2x = v2.x - v0.x, e2y = v2.y - v0.y, e2z = v2.z - v0.z;
    float e3x = v3.x - v0.x, e3y = v3.y - v0.y, e3z = v3.z - v0.z;

    float det = e1x * (e2y * e3z - e2z * e3y)
              - e1y * (e2x * e3z - e2z * e3x)
              + e1z * (e2x * e3y - e2y * e3x);
    __builtin_nontemporal_store(fabsf(det) * (1.0f / 6.0f), &out_area[i]);

    float q01 = e1x * e1x + e1y * e1y + e1z * e1z;
    float q02 = e2x * e2x + e2y * e2y + e2z * e2z;
    float q03 = e3x * e3x + e3y * e3y + e3z * e3z;
    float ax, ay, az;
    ax = v1.x - v2.x; ay = v1.y - v2.y; az = v1.z - v2.z;
    float q12 = ax * ax + ay * ay + az * az;
    ax = v1.x - v3.x; ay = v1.y - v3.y; az = v1.z - v3.z;
    float q13 = ax * ax + ay * ay + az * az;
    ax = v2.x - v3.x; ay = v2.y - v3.y; az = v2.z - v3.z;
    float q23 = ax * ax + ay * ay + az * az;

    float mn = fminf(fminf(fminf(q01, q02), fminf(q03, q12)), fminf(q13, q23));
    float el = sqrtf(mn);
    __builtin_nontemporal_store(1.0f - expf(-d * el), &out_alpha[i]);

    if (db > c0) atomicMax(vd + idx.x, db);
    if (db > c1) atomicMax(vd + idx.y, db);
    if (db > c2) atomicMax(vd + idx.z, db);
    if (db > c3) atomicMax(vd + idx.w, db);
}

// ---------------- tier-4: round-0 verified kernel ----------------
__global__ __launch_bounds__(256) void tet_kernel_fb(
    const float* __restrict__ verts,
    const int4*  __restrict__ indices,
    const float* __restrict__ density,
    float* __restrict__ out_area,
    float* __restrict__ out_alpha,
    unsigned int* __restrict__ vd,
    int T)
{
    int i = blockIdx.x * blockDim.x + threadIdx.x;
    if (i >= T) return;

    int4 idx = indices[i];
    float d = density[i];

    const float* p;
    p = verts + idx.x * 3; float v0x = p[0], v0y = p[1], v0z = p[2];
    p = verts + idx.y * 3; float v1x = p[0], v1y = p[1], v1z = p[2];
    p = verts + idx.z * 3; float v2x = p[0], v2y = p[1], v2z = p[2];
    p = verts + idx.w * 3; float v3x = p[0], v3y = p[1], v3z = p[2];

    float e1x = v1x - v0x, e1y = v1y - v0y, e1z = v1z - v0z;
    float e2x = v2x - v0x, e2y = v2y - v0y, e2z = v2z - v0z;
    float e3x = v3x - v0x, e3y = v3y - v0y, e3z = v3z - v0z;

    float det = e1x * (e2y * e3z - e2z * e3y)
              - e1y * (e2x * e3z - e2z * e3x)
              + e1z * (e2x * e3y - e2y * e3x);
    out_area[i] = fabsf(det) * (1.0f / 6.0f);

    float q01 = e1x * e1x + e1y * e1y + e1z * e1z;
    float q02 = e2x * e2x + e2y * e2y + e2z * e2z;
    float q03 = e3x * e3x + e3y * e3y + e3z * e3z;
    float ax, ay, az;
    ax = v1x - v2x; ay = v1y - v2y; az = v1z - v2z;
    float q12 = ax * ax + ay * ay + az * az;
    ax = v1x - v3x; ay = v1y - v3y; az = v1z - v3z;
    float q13 = ax * ax + ay * ay + az * az;
    ax = v2x - v3x; ay = v2y - v3y; az = v2z - v3z;
    float q23 = ax * ax + ay * ay + az * az;

    float mn = fminf(fminf(fminf(q01, q02), fminf(q03, q12)), fminf(q13, q23));
    float el = sqrtf(mn);
    out_alpha[i] = 1.0f - expf(-d * el);

    unsigned int db = __float_as_uint(d);
    atomicMax(vd + idx.x, db);
    atomicMax(vd + idx.y, db);
    atomicMax(vd + idx.z, db);
    atomicMax(vd + idx.w, db);
}

// ---------------- launch ----------------

extern "C" void kernel_launch(void* const* d_in, const int* in_sizes, int n_in,
                              void* d_out, int out_size, void* d_ws, size_t ws_size,
                              hipStream_t stream) {
    const float* verts   = (const float*)d_in[0];
    const int*   indices = (const int*)d_in[1];
    const float* density = (const float*)d_in[2];
    int T = in_sizes[2];        // 4,000,000 tets
    int V = in_sizes[0] / 3;    // 1,000,000 vertices

    float* out       = (float*)d_out;
    float* out_area  = out;
    float* out_alpha = out + (size_t)T;
    unsigned int* vd = (unsigned int*)(out + 2 * (size_t)T);

    const int block = 256;
    int n4 = V / 4;

    size_t pairsB = (size_t)NB * BCAP * sizeof(uint2);   // 128 MB
    size_t cntB   = (size_t)NB * sizeof(unsigned);
    size_t v4B    = (size_t)V * sizeof(float4);          // 16 MB

    // bucket capacity sanity: mean + 12*sigma must fit (plus runtime overflow path)
    double mean = 4.0 * (double)T / NB;
    bool capOK = (mean + 12.0 * __builtin_sqrt(mean) <= (double)BCAP);
    bool fastOK = (V % 4 == 0) && (V <= (NB << VSHIFT)) && capOK && d_ws;

    if (fastOK && ws_size >= pairsB + cntB + v4B) {
        uint2*    pairs  = (uint2*)d_ws;
        unsigned* gcnt   = (unsigned*)((char*)d_ws + pairsB);
        float4*   verts4 = (float4*)((char*)d_ws + pairsB + ((cntB + 255) & ~(size_t)255));

        zero_kernel<<<(n4 + block - 1) / block, block, 0, stream>>>((uint4*)vd, n4, gcnt);
        pad_verts_kernel<<<(V + block - 1) / block, block, 0, stream>>>(verts, verts4, V);
        geom_kernel_v4<<<(T + block - 1) / block, block, 0, stream>>>(
            verts4, indices, density, out_area, out_alpha, T);

        int tetsPerBlock = block * KT;
        bin_kernel<<<(T + tetsPerBlock - 1) / tetsPerBlock, block, 0, stream>>>(
            (const int4*)indices, density, pairs, gcnt, vd, T);

        int nbAct = (V + (1 << VSHIFT) - 1) >> VSHIFT;
        bucket_max_kernel<<<nbAct, 1024, 0, stream>>>(pairs, gcnt, vd, V);
    } else if (fastOK && ws_size >= pairsB + cntB) {
        uint2*    pairs = (uint2*)d_ws;
        unsigned* gcnt  = (unsigned*)((char*)d_ws + pairsB);

        zero_kernel<<<(n4 + block - 1) / block, block, 0, stream>>>((uint4*)vd, n4, gcnt);
        geom_kernel_raw<<<(T + block - 1) / block, block, 0, stream>>>(
            verts, indices, density, out_area, out_alpha, T);

        int tetsPerBlock = block * KT;
        bin_kernel<<<(T + tetsPerBlock - 1) / tetsPerBlock, block, 0, stream>>>(
            (const int4*)indices, density, pairs, gcnt, vd, T);

        int nbAct = (V + (1 << VSHIFT) - 1) >> VSHIFT;
        bucket_max_kernel<<<nbAct, 1024, 0, stream>>>(pairs, gcnt, vd, V);
    } else if (d_ws && ws_size >= v4B && (V % 4) == 0) {
        // tier-3: round-3 verified path
        zero_kernel<<<(n4 + block - 1) / block, block, 0, stream>>>((uint4*)vd, n4, nullptr);
        float4* verts4 = (float4*)d_ws;
        pad_verts_kernel<<<(V + block - 1) / block, block, 0, stream>>>(verts, verts4, V);
        tet_kernel_filter<<<(T + block - 1) / block, block, 0, stream>>>(
            verts4, indices, density, out_area, out_alpha, vd, T);
    } else {
        zero_kernel<<<(n4 + block - 1) / block, block, 0, stream>>>((uint4*)vd, n4, nullptr);
        tet_kernel_fb<<<(T + block - 1) / block, block, 0, stream>>>(
            verts, (const int4*)indices, density, out_area, out_alpha, vd, T);
    }
}

// Round 5
// 449.981 us; speedup vs baseline: 1.6683x; 1.2025x over previous
//
#include <hip/hip_runtime.h>

// clang-native vector types: __builtin_nontemporal_* rejects HIP_vector_type wrappers.
typedef int nt_int4 __attribute__((ext_vector_type(4)));

#define NB     256        // vertex buckets (== bin block threads)
#define VSHIFT 12         // 4096 verts per bucket -> 16 KB LDS table
#define BMASK  ((1 << VSHIFT) - 1)
#define BCAP   65536      // pairs per bucket capacity (mean 62.5K + 24 sigma)
#define RT     4          // tets per thread per round (bin2)
#define NR     4          // rounds (bin2)  -> 4096 tets per block

// Zero vd region (harness poisons d_out) and the global bucket counters.
__global__ __launch_bounds__(256) void zero_kernel(uint4* __restrict__ vd4, int n4,
                                                   unsigned* __restrict__ gcnt) {
    int i = blockIdx.x * blockDim.x + threadIdx.x;
    if (i < n4) vd4[i] = make_uint4(0u, 0u, 0u, 0u);
    if (gcnt && i < NB) gcnt[i] = 0u;
}

// Pad 12B-strided verts to 16B float4 so gathers are one aligned dwordx4.
__global__ __launch_bounds__(256) void pad_verts_kernel(const float* __restrict__ verts,
                                                        float4* __restrict__ verts4, int V) {
    int i = blockIdx.x * blockDim.x + threadIdx.x;
    if (i < V) {
        const float* p = verts + (size_t)i * 3;
        verts4[i] = make_float4(p[0], p[1], p[2], 0.f);
    }
}

// ---- pure geometry: no vd state touched ----
__global__ __launch_bounds__(256) void geom_kernel_v4(
    const float4* __restrict__ verts4,
    const int*   __restrict__ indices,
    const float* __restrict__ density,
    float* __restrict__ out_area,
    float* __restrict__ out_alpha,
    int T)
{
    int i = blockIdx.x * blockDim.x + threadIdx.x;
    if (i >= T) return;

    nt_int4 idx = __builtin_nontemporal_load((const nt_int4*)indices + i);
    float d     = __builtin_nontemporal_load(&density[i]);

    float4 v0 = verts4[idx.x];
    float4 v1 = verts4[idx.y];
    float4 v2 = verts4[idx.z];
    float4 v3 = verts4[idx.w];

    float e1x = v1.x - v0.x, e1y = v1.y - v0.y, e1z = v1.z - v0.z;
    float e2x = v2.x - v0.x, e2y = v2.y - v0.y, e2z = v2.z - v0.z;
    float e3x = v3.x - v0.x, e3y = v3.y - v0.y, e3z = v3.z - v0.z;

    float det = e1x * (e2y * e3z - e2z * e3y)
              - e1y * (e2x * e3z - e2z * e3x)
              + e1z * (e2x * e3y - e2y * e3x);
    __builtin_nontemporal_store(fabsf(det) * (1.0f / 6.0f), &out_area[i]);

    float q01 = e1x * e1x + e1y * e1y + e1z * e1z;
    float q02 = e2x * e2x + e2y * e2y + e2z * e2z;
    float q03 = e3x * e3x + e3y * e3y + e3z * e3z;
    float ax, ay, az;
    ax = v1.x - v2.x; ay = v1.y - v2.y; az = v1.z - v2.z;
    float q12 = ax * ax + ay * ay + az * az;
    ax = v1.x - v3.x; ay = v1.y - v3.y; az = v1.z - v3.z;
    float q13 = ax * ax + ay * ay + az * az;
    ax = v2.x - v3.x; ay = v2.y - v3.y; az = v2.z - v3.z;
    float q23 = ax * ax + ay * ay + az * az;

    float mn = fminf(fminf(fminf(q01, q02), fminf(q03, q12)), fminf(q13, q23));
    float el = sqrtf(mn);
    __builtin_nontemporal_store(1.0f - expf(-d * el), &out_alpha[i]);
}

// Raw-verts variant (used when ws can't hold verts4 too).
__global__ __launch_bounds__(256) void geom_kernel_raw(
    const float* __restrict__ verts,
    const int*   __restrict__ indices,
    const float* __restrict__ density,
    float* __restrict__ out_area,
    float* __restrict__ out_alpha,
    int T)
{
    int i = blockIdx.x * blockDim.x + threadIdx.x;
    if (i >= T) return;

    nt_int4 idx = __builtin_nontemporal_load((const nt_int4*)indices + i);
    float d     = __builtin_nontemporal_load(&density[i]);

    const float* p;
    p = verts + (size_t)idx.x * 3; float v0x = p[0], v0y = p[1], v0z = p[2];
    p = verts + (size_t)idx.y * 3; float v1x = p[0], v1y = p[1], v1z = p[2];
    p = verts + (size_t)idx.z * 3; float v2x = p[0], v2y = p[1], v2z = p[2];
    p = verts + (size_t)idx.w * 3; float v3x = p[0], v3y = p[1], v3z = p[2];

    float e1x = v1x - v0x, e1y = v1y - v0y, e1z = v1z - v0z;
    float e2x = v2x - v0x, e2y = v2y - v0y, e2z = v2z - v0z;
    float e3x = v3x - v0x, e3y = v3y - v0y, e3z = v3z - v0z;

    float det = e1x * (e2y * e3z - e2z * e3y)
              - e1y * (e2x * e3z - e2z * e3x)
              + e1z * (e2x * e3y - e2y * e3x);
    __builtin_nontemporal_store(fabsf(det) * (1.0f / 6.0f), &out_area[i]);

    float q01 = e1x * e1x + e1y * e1y + e1z * e1z;
    float q02 = e2x * e2x + e2y * e2y + e2z * e2z;
    float q03 = e3x * e3x + e3y * e3y + e3z * e3z;
    float ax, ay, az;
    ax = v1x - v2x; ay = v1y - v2y; az = v1z - v2z;
    float q12 = ax * ax + ay * ay + az * az;
    ax = v1x - v3x; ay = v1y - v3y; az = v1z - v3z;
    float q13 = ax * ax + ay * ay + az * az;
    ax = v2x - v3x; ay = v2y - v3y; az = v2z - v3z;
    float q23 = ax * ax + ay * ay + az * az;

    float mn = fminf(fminf(fminf(q01, q02), fminf(q03, q12)), fminf(q13, q23));
    float el = sqrtf(mn);
    __builtin_nontemporal_store(1.0f - expf(-d * el), &out_alpha[i]);
}

// ---- bin v2: LDS-staged, bucket-compacted rounds -> coalesced full-line pair writes ----
// Round 4 measured 445 MB writeback for 128 MB of pairs (8B scatter => 32B partial
// sectors). Here each round compacts 4096 pairs by bucket in LDS, then flushes
// linearly: consecutive lanes -> consecutive global addresses within segments.
__global__ __launch_bounds__(256) void bin2_kernel(
    const int4*  __restrict__ idx4,
    const float* __restrict__ dens,
    uint2*       __restrict__ pairs,   // NB x BCAP
    unsigned*    __restrict__ gcnt,    // NB
    unsigned*    __restrict__ vd,      // overflow fallback target (zeroed)
    int T)
{
    __shared__ unsigned s_cnt[NB];    // phase-1 block counts, then per-round counts
    __shared__ unsigned s_run[NB];    // running global base per bucket
    __shared__ unsigned s_roff[NB];   // exclusive LDS offsets for current round
    __shared__ unsigned s_wc[NB];     // per-round write cursors
    __shared__ unsigned s_scan[NB];   // scan scratch
    __shared__ uint2    stage[256 * RT * 4];  // 4096 pairs = 32 KB

    int tid  = threadIdx.x;
    int base = blockIdx.x * (256 * RT * NR);

    // phase 1: count the whole block chunk (reads stay L2-hot for the rounds)
    s_cnt[tid] = 0u;
    __syncthreads();
    for (int k = 0; k < RT * NR; ++k) {
        int i = base + k * 256 + tid;
        if (i < T) {
            int4 q = idx4[i];
            atomicAdd(&s_cnt[(unsigned)q.x >> VSHIFT], 1u);
            atomicAdd(&s_cnt[(unsigned)q.y >> VSHIFT], 1u);
            atomicAdd(&s_cnt[(unsigned)q.z >> VSHIFT], 1u);
            atomicAdd(&s_cnt[(unsigned)q.w >> VSHIFT], 1u);
        }
    }
    __syncthreads();

    // phase 2: one global bump per (block, bucket) — 250K total, measured cheap
    s_run[tid] = atomicAdd(&gcnt[tid], s_cnt[tid]);
    __syncthreads();

    // phase 3: rounds of RT tets/thread
    for (int r = 0; r < NR; ++r) {
        int4  q[RT];
        float dd[RT];
        bool  vl[RT];
#pragma unroll
        for (int k = 0; k < RT; ++k) {
            int i = base + (r * RT + k) * 256 + tid;
            vl[k] = (i < T);
            if (vl[k]) { q[k] = idx4[i]; dd[k] = dens[i]; }
        }

        // round histogram
        s_cnt[tid] = 0u;
        __syncthreads();
#pragma unroll
        for (int k = 0; k < RT; ++k) if (vl[k]) {
            atomicAdd(&s_cnt[(unsigned)q[k].x >> VSHIFT], 1u);
            atomicAdd(&s_cnt[(unsigned)q[k].y >> VSHIFT], 1u);
            atomicAdd(&s_cnt[(unsigned)q[k].z >> VSHIFT], 1u);
            atomicAdd(&s_cnt[(unsigned)q[k].w >> VSHIFT], 1u);
        }
        __syncthreads();

        // exclusive scan (Hillis-Steele over 256 entries)
        unsigned x = s_cnt[tid];
        s_scan[tid] = x;
        __syncthreads();
        for (int s = 1; s < NB; s <<= 1) {
            unsigned t = (tid >= s) ? s_scan[tid - s] : 0u;
            __syncthreads();
            s_scan[tid] += t;
            __syncthreads();
        }
        s_roff[tid] = s_scan[tid] - x;
        s_wc[tid]   = 0u;
        __syncthreads();
        unsigned npairs = s_scan[NB - 1];

        // scatter round pairs into bucket-compacted staging
#pragma unroll
        for (int k = 0; k < RT; ++k) if (vl[k]) {
            unsigned db = __float_as_uint(dd[k]);
            unsigned vv[4] = { (unsigned)q[k].x, (unsigned)q[k].y,
                               (unsigned)q[k].z, (unsigned)q[k].w };
#pragma unroll
            for (int j = 0; j < 4; ++j) {
                unsigned b    = vv[j] >> VSHIFT;
                unsigned slot = s_roff[b] + atomicAdd(&s_wc[b], 1u);
                stage[slot] = make_uint2(vv[j], db);
            }
        }
        __syncthreads();

        // coalesced flush: lane-consecutive staging slots -> consecutive global
        for (unsigned l = tid; l < npairs; l += 256) {
            uint2 e = stage[l];
            unsigned b  = e.x >> VSHIFT;             // bucket derivable from vertex id
            unsigned rr = s_run[b] + (l - s_roff[b]);
            if (rr < BCAP) pairs[(size_t)b * BCAP + rr] = e;
            else           atomicMax(vd + e.x, e.y); // astronomically rare; correct
        }
        __syncthreads();

        // advance running bases
        s_run[tid] += s_cnt[tid];
        __syncthreads();
    }
}

// ---- per-bucket max in LDS: zero global atomics ----
__global__ __launch_bounds__(1024) void bucket_max_kernel(
    const uint2*    __restrict__ pairs,
    const unsigned* __restrict__ gcnt,
    unsigned*       __restrict__ vd,
    int V)
{
    __shared__ unsigned tbl[1 << VSHIFT];
    int b   = blockIdx.x;
    int tid = threadIdx.x;

    for (int j = tid; j < (1 << VSHIFT); j += 1024) tbl[j] = 0u;
    __syncthreads();

    unsigned cnt = gcnt[b];
    if (cnt > BCAP) cnt = BCAP;
    const uint2* p = pairs + (size_t)b * BCAP;
    for (unsigned i = tid; i < cnt; i += 1024) {
        uint2 e = p[i];
        atomicMax(&tbl[e.x & BMASK], e.y);   // ds_max_u32: on-chip
    }
    __syncthreads();

    int vbase = b << VSHIFT;
    for (int j = tid; j < (1 << VSHIFT); j += 1024) {
        int v = vbase + j;
        if (v < V) {
            unsigned cur = vd[v];            // merge overflow-fallback atomics
            unsigned t   = tbl[j];
            vd[v] = cur > t ? cur : t;
        }
    }
}

// ---------------- tier-3: round-3 verified kernel (read-filtered atomics) ----------------
__global__ __launch_bounds__(256) void tet_kernel_filter(
    const float4* __restrict__ verts4,
    const int*   __restrict__ indices,
    const float* __restrict__ density,
    float* __restrict__ out_area,
    float* __restrict__ out_alpha,
    unsigned int* __restrict__ vd,
    int T)
{
    int i = blockIdx.x * blockDim.x + threadIdx.x;
    if (i >= T) return;

    nt_int4 idx = __builtin_nontemporal_load((const nt_int4*)indices + i);
    float d     = __builtin_nontemporal_load(&density[i]);
    unsigned int db = __float_as_uint(d);

    unsigned int c0 = vd[idx.x];
    unsigned int c1 = vd[idx.y];
    unsigned int c2 = vd[idx.z];
    unsigned int c3 = vd[idx.w];

    float4 v0 = verts4[idx.x];
    float4 v1 = verts4[idx.y];
    float4 v2 = verts4[idx.z];
    float4 v3 = verts4[idx.w];

    float e1x = v1.x - v0.x, e1y = v1.y - v0.y, e1z = v1.z - v0.z;
    float e2x = v2.x - v0.x, e2y = v2.y - v0.y, e2z = v2.z - v0.z;
    float e3x = v3.x - v0.x, e3y = v3.y - v0.y, e3z = v3.z - v0.z;

    float det = e1x * (e2y * e3z - e2z * e3y)
              - e1y * (e2x * e3z - e2z * e3x)
              + e1z * (e2x * e3y - e2y * e3x);
    __builtin_nontemporal_store(fabsf(det) * (1.0f / 6.0f), &out_area[i]);

    float q01 = e1x * e1x + e1y * e1y + e1z * e1z;
    float q02 = e2x * e2x + e2y * e2y + e2z * e2z;
    float q03 = e3x * e3x + e3y * e3y + e3z * e3z;
    float ax, ay, az;
    ax = v1.x - v2.x; ay = v1.y - v2.y; az = v1.z - v2.z;
    float q12 = ax * ax + ay * ay + az * az;
    ax = v1.x - v3.x; ay = v1.y - v3.y; az = v1.z - v3.z;
    float q13 = ax * ax + ay * ay + az * az;
    ax = v2.x - v3.x; ay = v2.y - v3.y; az = v2.z - v3.z;
    float q23 = ax * ax + ay * ay + az * az;

    float mn = fminf(fminf(fminf(q01, q02), fminf(q03, q12)), fminf(q13, q23));
    float el = sqrtf(mn);
    __builtin_nontemporal_store(1.0f - expf(-d * el), &out_alpha[i]);

    if (db > c0) atomicMax(vd + idx.x, db);
    if (db > c1) atomicMax(vd + idx.y, db);
    if (db > c2) atomicMax(vd + idx.z, db);
    if (db > c3) atomicMax(vd + idx.w, db);
}

// ---------------- tier-4: round-0 verified kernel ----------------
__global__ __launch_bounds__(256) void tet_kernel_fb(
    const float* __restrict__ verts,
    const int4*  __restrict__ indices,
    const float* __restrict__ density,
    float* __restrict__ out_area,
    float* __restrict__ out_alpha,
    unsigned int* __restrict__ vd,
    int T)
{
    int i = blockIdx.x * blockDim.x + threadIdx.x;
    if (i >= T) return;

    int4 idx = indices[i];
    float d = density[i];

    const float* p;
    p = verts + idx.x * 3; float v0x = p[0], v0y = p[1], v0z = p[2];
    p = verts + idx.y * 3; float v1x = p[0], v1y = p[1], v1z = p[2];
    p = verts + idx.z * 3; float v2x = p[0], v2y = p[1], v2z = p[2];
    p = verts + idx.w * 3; float v3x = p[0], v3y = p[1], v3z = p[2];

    float e1x = v1x - v0x, e1y = v1y - v0y, e1z = v1z - v0z;
    float e2x = v2x - v0x, e2y = v2y - v0y, e2z = v2z - v0z;
    float e3x = v3x - v0x, e3y = v3y - v0y, e3z = v3z - v0z;

    float det = e1x * (e2y * e3z - e2z * e3y)
              - e1y * (e2x * e3z - e2z * e3x)
              + e1z * (e2x * e3y - e2y * e3x);
    out_area[i] = fabsf(det) * (1.0f / 6.0f);

    float q01 = e1x * e1x + e1y * e1y + e1z * e1z;
    float q02 = e2x * e2x + e2y * e2y + e2z * e2z;
    float q03 = e3x * e3x + e3y * e3y + e3z * e3z;
    float ax, ay, az;
    ax = v1x - v2x; ay = v1y - v2y; az = v1z - v2z;
    float q12 = ax * ax + ay * ay + az * az;
    ax = v1x - v3x; ay = v1y - v3y; az = v1z - v3z;
    float q13 = ax * ax + ay * ay + az * az;
    ax = v2x - v3x; ay = v2y - v3y; az = v2z - v3z;
    float q23 = ax * ax + ay * ay + az * az;

    float mn = fminf(fminf(fminf(q01, q02), fminf(q03, q12)), fminf(q13, q23));
    float el = sqrtf(mn);
    out_alpha[i] = 1.0f - expf(-d * el);

    unsigned int db = __float_as_uint(d);
    atomicMax(vd + idx.x, db);
    atomicMax(vd + idx.y, db);
    atomicMax(vd + idx.z, db);
    atomicMax(vd + idx.w, db);
}

// ---------------- launch ----------------

extern "C" void kernel_launch(void* const* d_in, const int* in_sizes, int n_in,
                              void* d_out, int out_size, void* d_ws, size_t ws_size,
                              hipStream_t stream) {
    const float* verts   = (const float*)d_in[0];
    const int*   indices = (const int*)d_in[1];
    const float* density = (const float*)d_in[2];
    int T = in_sizes[2];        // 4,000,000 tets
    int V = in_sizes[0] / 3;    // 1,000,000 vertices

    float* out       = (float*)d_out;
    float* out_area  = out;
    float* out_alpha = out + (size_t)T;
    unsigned int* vd = (unsigned int*)(out + 2 * (size_t)T);

    const int block = 256;
    int n4 = V / 4;

    size_t pairsB = (size_t)NB * BCAP * sizeof(uint2);   // 128 MB
    size_t cntB   = (size_t)NB * sizeof(unsigned);
    size_t v4B    = (size_t)V * sizeof(float4);          // 16 MB

    double mean = 4.0 * (double)T / NB;
    bool capOK = (mean + 12.0 * __builtin_sqrt(mean) <= (double)BCAP);
    bool fastOK = (V % 4 == 0) && (V <= (NB << VSHIFT)) && capOK && d_ws;

    int tetsPerBlock = block * RT * NR;   // 4096

    if (fastOK && ws_size >= pairsB + cntB + v4B) {
        uint2*    pairs  = (uint2*)d_ws;
        unsigned* gcnt   = (unsigned*)((char*)d_ws + pairsB);
        float4*   verts4 = (float4*)((char*)d_ws + pairsB + ((cntB + 255) & ~(size_t)255));

        zero_kernel<<<(n4 + block - 1) / block, block, 0, stream>>>((uint4*)vd, n4, gcnt);
        pad_verts_kernel<<<(V + block - 1) / block, block, 0, stream>>>(verts, verts4, V);
        geom_kernel_v4<<<(T + block - 1) / block, block, 0, stream>>>(
            verts4, indices, density, out_area, out_alpha, T);

        bin2_kernel<<<(T + tetsPerBlock - 1) / tetsPerBlock, block, 0, stream>>>(
            (const int4*)indices, density, pairs, gcnt, vd, T);

        int nbAct = (V + (1 << VSHIFT) - 1) >> VSHIFT;
        bucket_max_kernel<<<nbAct, 1024, 0, stream>>>(pairs, gcnt, vd, V);
    } else if (fastOK && ws_size >= pairsB + cntB) {
        uint2*    pairs = (uint2*)d_ws;
        unsigned* gcnt  = (unsigned*)((char*)d_ws + pairsB);

        zero_kernel<<<(n4 + block - 1) / block, block, 0, stream>>>((uint4*)vd, n4, gcnt);
        geom_kernel_raw<<<(T + block - 1) / block, block, 0, stream>>>(
            verts, indices, density, out_area, out_alpha, T);

        bin2_kernel<<<(T + tetsPerBlock - 1) / tetsPerBlock, block, 0, stream>>>(
            (const int4*)indices, density, pairs, gcnt, vd, T);

        int nbAct = (V + (1 << VSHIFT) - 1) >> VSHIFT;
        bucket_max_kernel<<<nbAct, 1024, 0, stream>>>(pairs, gcnt, vd, V);
    } else if (d_ws && ws_size >= v4B && (V % 4) == 0) {
        zero_kernel<<<(n4 + block - 1) / block, block, 0, stream>>>((uint4*)vd, n4, nullptr);
        float4* verts4 = (float4*)d_ws;
        pad_verts_kernel<<<(V + block - 1) / block, block, 0, stream>>>(verts, verts4, V);
        tet_kernel_filter<<<(T + block - 1) / block, block, 0, stream>>>(
            verts4, indices, density, out_area, out_alpha, vd, T);
    } else {
        zero_kernel<<<(n4 + block - 1) / block, block, 0, stream>>>((uint4*)vd, n4, nullptr);
        tet_kernel_fb<<<(T + block - 1) / block, block, 0, stream>>>(
            verts, (const int4*)indices, density, out_area, out_alpha, vd, T);
    }
}

// Round 6
// 429.014 us; speedup vs baseline: 1.7498x; 1.0489x over previous
//
#include <hip/hip_runtime.h>

// clang-native vector types: __builtin_nontemporal_* rejects HIP_vector_type wrappers.
typedef int nt_int4 __attribute__((ext_vector_type(4)));

#define NB     256        // vertex buckets (== bin block threads)
#define VSHIFT 12         // 4096 verts per bucket -> 16 KB LDS table
#define BMASK  ((1 << VSHIFT) - 1)
#define BCAP   65536      // pairs per bucket capacity (mean 62.5K + 24 sigma)
#define RT     4          // tets per thread per round
#define NR     4          // rounds -> 4096 tets per block

// Zero vd region (harness poisons d_out) and the global bucket counters.
__global__ __launch_bounds__(256) void zero_kernel(uint4* __restrict__ vd4, int n4,
                                                   unsigned* __restrict__ gcnt) {
    int i = blockIdx.x * blockDim.x + threadIdx.x;
    if (i < n4) vd4[i] = make_uint4(0u, 0u, 0u, 0u);
    if (gcnt && i < NB) gcnt[i] = 0u;
}

// Pad 12B-strided verts to 16B float4 so gathers are one aligned dwordx4.
__global__ __launch_bounds__(256) void pad_verts_kernel(const float* __restrict__ verts,
                                                        float4* __restrict__ verts4, int V) {
    int i = blockIdx.x * blockDim.x + threadIdx.x;
    if (i < V) {
        const float* p = verts + (size_t)i * 3;
        verts4[i] = make_float4(p[0], p[1], p[2], 0.f);
    }
}

// ---- fused geometry + binning ----
// Round-5 profile: geom (gather-read-path bound, 214us, VALU 5%, writes idle) ran
// SERIALLY before bin2 (LDS/write-path bound). Fusing overlaps the orthogonal
// bottlenecks and reads indices once instead of twice (phase-3 re-read is L2-hot).
__global__ __launch_bounds__(256) void fused_geom_bin_kernel(
    const float4* __restrict__ verts4,
    const int4*  __restrict__ idx4,
    const float* __restrict__ dens,
    float* __restrict__ out_area,
    float* __restrict__ out_alpha,
    uint2*       __restrict__ pairs,   // NB x BCAP
    unsigned*    __restrict__ gcnt,    // NB
    unsigned*    __restrict__ vd,      // overflow fallback target (zeroed)
    int T)
{
    __shared__ unsigned s_cnt[NB];
    __shared__ unsigned s_run[NB];
    __shared__ unsigned s_roff[NB];
    __shared__ unsigned s_wc[NB];
    __shared__ unsigned s_scan[NB];
    __shared__ uint2    stage[256 * RT * 4];  // 4096 pairs = 32 KB

    int tid  = threadIdx.x;
    int base = blockIdx.x * (256 * RT * NR);

    // phase 1: count the whole block chunk (idx stays L2-hot for the rounds)
    s_cnt[tid] = 0u;
    __syncthreads();
    for (int k = 0; k < RT * NR; ++k) {
        int i = base + k * 256 + tid;
        if (i < T) {
            int4 q = idx4[i];
            atomicAdd(&s_cnt[(unsigned)q.x >> VSHIFT], 1u);
            atomicAdd(&s_cnt[(unsigned)q.y >> VSHIFT], 1u);
            atomicAdd(&s_cnt[(unsigned)q.z >> VSHIFT], 1u);
            atomicAdd(&s_cnt[(unsigned)q.w >> VSHIFT], 1u);
        }
    }
    __syncthreads();

    // phase 2: one global bump per (block, bucket)
    s_run[tid] = atomicAdd(&gcnt[tid], s_cnt[tid]);
    __syncthreads();

    // phase 3: rounds of RT tets/thread, geometry fused in
    for (int r = 0; r < NR; ++r) {
        int4  q[RT];
        float dd[RT];
        bool  vl[RT];
#pragma unroll
        for (int k = 0; k < RT; ++k) {
            int i = base + (r * RT + k) * 256 + tid;
            vl[k] = (i < T);
            if (vl[k]) { q[k] = idx4[i]; dd[k] = dens[i]; }
        }

        // geometry: gathers + register compute + streamed outputs
#pragma unroll
        for (int k = 0; k < RT; ++k) if (vl[k]) {
            int i = base + (r * RT + k) * 256 + tid;
            float4 v0 = verts4[q[k].x];
            float4 v1 = verts4[q[k].y];
            float4 v2 = verts4[q[k].z];
            float4 v3 = verts4[q[k].w];

            float e1x = v1.x - v0.x, e1y = v1.y - v0.y, e1z = v1.z - v0.z;
            float e2x = v2.x - v0.x, e2y = v2.y - v0.y, e2z = v2.z - v0.z;
            float e3x = v3.x - v0.x, e3y = v3.y - v0.y, e3z = v3.z - v0.z;

            float det = e1x * (e2y * e3z - e2z * e3y)
                      - e1y * (e2x * e3z - e2z * e3x)
                      + e1z * (e2x * e3y - e2y * e3x);
            __builtin_nontemporal_store(fabsf(det) * (1.0f / 6.0f), &out_area[i]);

            float q01 = e1x * e1x + e1y * e1y + e1z * e1z;
            float q02 = e2x * e2x + e2y * e2y + e2z * e2z;
            float q03 = e3x * e3x + e3y * e3y + e3z * e3z;
            float ax, ay, az;
            ax = v1.x - v2.x; ay = v1.y - v2.y; az = v1.z - v2.z;
            float q12 = ax * ax + ay * ay + az * az;
            ax = v1.x - v3.x; ay = v1.y - v3.y; az = v1.z - v3.z;
            float q13 = ax * ax + ay * ay + az * az;
            ax = v2.x - v3.x; ay = v2.y - v3.y; az = v2.z - v3.z;
            float q23 = ax * ax + ay * ay + az * az;

            float mn = fminf(fminf(fminf(q01, q02), fminf(q03, q12)), fminf(q13, q23));
            float el = sqrtf(mn);
            __builtin_nontemporal_store(1.0f - expf(-dd[k] * el), &out_alpha[i]);
        }

        // round histogram
        s_cnt[tid] = 0u;
        __syncthreads();
#pragma unroll
        for (int k = 0; k < RT; ++k) if (vl[k]) {
            atomicAdd(&s_cnt[(unsigned)q[k].x >> VSHIFT], 1u);
            atomicAdd(&s_cnt[(unsigned)q[k].y >> VSHIFT], 1u);
            atomicAdd(&s_cnt[(unsigned)q[k].z >> VSHIFT], 1u);
            atomicAdd(&s_cnt[(unsigned)q[k].w >> VSHIFT], 1u);
        }
        __syncthreads();

        // exclusive scan (Hillis-Steele over 256 entries)
        unsigned x = s_cnt[tid];
        s_scan[tid] = x;
        __syncthreads();
        for (int s = 1; s < NB; s <<= 1) {
            unsigned t = (tid >= s) ? s_scan[tid - s] : 0u;
            __syncthreads();
            s_scan[tid] += t;
            __syncthreads();
        }
        s_roff[tid] = s_scan[tid] - x;
        s_wc[tid]   = 0u;
        __syncthreads();
        unsigned npairs = s_scan[NB - 1];

        // scatter round pairs into bucket-compacted staging
#pragma unroll
        for (int k = 0; k < RT; ++k) if (vl[k]) {
            unsigned db = __float_as_uint(dd[k]);
            unsigned vv[4] = { (unsigned)q[k].x, (unsigned)q[k].y,
                               (unsigned)q[k].z, (unsigned)q[k].w };
#pragma unroll
            for (int j = 0; j < 4; ++j) {
                unsigned b    = vv[j] >> VSHIFT;
                unsigned slot = s_roff[b] + atomicAdd(&s_wc[b], 1u);
                stage[slot] = make_uint2(vv[j], db);
            }
        }
        __syncthreads();

        // coalesced flush: lane-consecutive staging slots -> consecutive global
        for (unsigned l = tid; l < npairs; l += 256) {
            uint2 e = stage[l];
            unsigned b  = e.x >> VSHIFT;
            unsigned rr = s_run[b] + (l - s_roff[b]);
            if (rr < BCAP) pairs[(size_t)b * BCAP + rr] = e;
            else           atomicMax(vd + e.x, e.y); // astronomically rare; correct
        }
        __syncthreads();

        // advance running bases
        s_run[tid] += s_cnt[tid];
        __syncthreads();
    }
}

// ---- per-bucket max in LDS: zero global atomics ----
__global__ __launch_bounds__(1024) void bucket_max_kernel(
    const uint2*    __restrict__ pairs,
    const unsigned* __restrict__ gcnt,
    unsigned*       __restrict__ vd,
    int V)
{
    __shared__ unsigned tbl[1 << VSHIFT];
    int b   = blockIdx.x;
    int tid = threadIdx.x;

    for (int j = tid; j < (1 << VSHIFT); j += 1024) tbl[j] = 0u;
    __syncthreads();

    unsigned cnt = gcnt[b];
    if (cnt > BCAP) cnt = BCAP;
    const uint2* p = pairs + (size_t)b * BCAP;
    for (unsigned i = tid; i < cnt; i += 1024) {
        uint2 e = p[i];
        atomicMax(&tbl[e.x & BMASK], e.y);   // ds_max_u32: on-chip
    }
    __syncthreads();

    int vbase = b << VSHIFT;
    for (int j = tid; j < (1 << VSHIFT); j += 1024) {
        int v = vbase + j;
        if (v < V) {
            unsigned cur = vd[v];            // merge overflow-fallback atomics
            unsigned t   = tbl[j];
            vd[v] = cur > t ? cur : t;
        }
    }
}

// ---------------- tier-3: round-3 verified kernel (read-filtered atomics) ----------------
__global__ __launch_bounds__(256) void tet_kernel_filter(
    const float4* __restrict__ verts4,
    const int*   __restrict__ indices,
    const float* __restrict__ density,
    float* __restrict__ out_area,
    float* __restrict__ out_alpha,
    unsigned int* __restrict__ vd,
    int T)
{
    int i = blockIdx.x * blockDim.x + threadIdx.x;
    if (i >= T) return;

    nt_int4 idx = __builtin_nontemporal_load((const nt_int4*)indices + i);
    float d     = __builtin_nontemporal_load(&density[i]);
    unsigned int db = __float_as_uint(d);

    unsigned int c0 = vd[idx.x];
    unsigned int c1 = vd[idx.y];
    unsigned int c2 = vd[idx.z];
    unsigned int c3 = vd[idx.w];

    float4 v0 = verts4[idx.x];
    float4 v1 = verts4[idx.y];
    float4 v2 = verts4[idx.z];
    float4 v3 = verts4[idx.w];

    float e1x = v1.x - v0.x, e1y = v1.y - v0.y, e1z = v1.z - v0.z;
    float e2x = v2.x - v0.x, e2y = v2.y - v0.y, e2z = v2.z - v0.z;
    float e3x = v3.x - v0.x, e3y = v3.y - v0.y, e3z = v3.z - v0.z;

    float det = e1x * (e2y * e3z - e2z * e3y)
              - e1y * (e2x * e3z - e2z * e3x)
              + e1z * (e2x * e3y - e2y * e3x);
    __builtin_nontemporal_store(fabsf(det) * (1.0f / 6.0f), &out_area[i]);

    float q01 = e1x * e1x + e1y * e1y + e1z * e1z;
    float q02 = e2x * e2x + e2y * e2y + e2z * e2z;
    float q03 = e3x * e3x + e3y * e3y + e3z * e3z;
    float ax, ay, az;
    ax = v1.x - v2.x; ay = v1.y - v2.y; az = v1.z - v2.z;
    float q12 = ax * ax + ay * ay + az * az;
    ax = v1.x - v3.x; ay = v1.y - v3.y; az = v1.z - v3.z;
    float q13 = ax * ax + ay * ay + az * az;
    ax = v2.x - v3.x; ay = v2.y - v3.y; az = v2.z - v3.z;
    float q23 = ax * ax + ay * ay + az * az;

    float mn = fminf(fminf(fminf(q01, q02), fminf(q03, q12)), fminf(q13, q23));
    float el = sqrtf(mn);
    __builtin_nontemporal_store(1.0f - expf(-d * el), &out_alpha[i]);

    if (db > c0) atomicMax(vd + idx.x, db);
    if (db > c1) atomicMax(vd + idx.y, db);
    if (db > c2) atomicMax(vd + idx.z, db);
    if (db > c3) atomicMax(vd + idx.w, db);
}

// ---------------- tier-4: round-0 verified kernel ----------------
__global__ __launch_bounds__(256) void tet_kernel_fb(
    const float* __restrict__ verts,
    const int4*  __restrict__ indices,
    const float* __restrict__ density,
    float* __restrict__ out_area,
    float* __restrict__ out_alpha,
    unsigned int* __restrict__ vd,
    int T)
{
    int i = blockIdx.x * blockDim.x + threadIdx.x;
    if (i >= T) return;

    int4 idx = indices[i];
    float d = density[i];

    const float* p;
    p = verts + idx.x * 3; float v0x = p[0], v0y = p[1], v0z = p[2];
    p = verts + idx.y * 3; float v1x = p[0], v1y = p[1], v1z = p[2];
    p = verts + idx.z * 3; float v2x = p[0], v2y = p[1], v2z = p[2];
    p = verts + idx.w * 3; float v3x = p[0], v3y = p[1], v3z = p[2];

    float e1x = v1x - v0x, e1y = v1y - v0y, e1z = v1z - v0z;
    float e2x = v2x - v0x, e2y = v2y - v0y, e2z = v2z - v0z;
    float e3x = v3x - v0x, e3y = v3y - v0y, e3z = v3z - v0z;

    float det = e1x * (e2y * e3z - e2z * e3y)
              - e1y * (e2x * e3z - e2z * e3x)
              + e1z * (e2x * e3y - e2y * e3x);
    out_area[i] = fabsf(det) * (1.0f / 6.0f);

    float q01 = e1x * e1x + e1y * e1y + e1z * e1z;
    float q02 = e2x * e2x + e2y * e2y + e2z * e2z;
    float q03 = e3x * e3x + e3y * e3y + e3z * e3z;
    float ax, ay, az;
    ax = v1x - v2x; ay = v1y - v2y; az = v1z - v2z;
    float q12 = ax * ax + ay * ay + az * az;
    ax = v1x - v3x; ay = v1y - v3y; az = v1z - v3z;
    float q13 = ax * ax + ay * ay + az * az;
    ax = v2x - v3x; ay = v2y - v3y; az = v2z - v3z;
    float q23 = ax * ax + ay * ay + az * az;

    float mn = fminf(fminf(fminf(q01, q02), fminf(q03, q12)), fminf(q13, q23));
    float el = sqrtf(mn);
    out_alpha[i] = 1.0f - expf(-d * el);

    unsigned int db = __float_as_uint(d);
    atomicMax(vd + idx.x, db);
    atomicMax(vd + idx.y, db);
    atomicMax(vd + idx.z, db);
    atomicMax(vd + idx.w, db);
}

// ---------------- launch ----------------

extern "C" void kernel_launch(void* const* d_in, const int* in_sizes, int n_in,
                              void* d_out, int out_size, void* d_ws, size_t ws_size,
                              hipStream_t stream) {
    const float* verts   = (const float*)d_in[0];
    const int*   indices = (const int*)d_in[1];
    const float* density = (const float*)d_in[2];
    int T = in_sizes[2];        // 4,000,000 tets
    int V = in_sizes[0] / 3;    // 1,000,000 vertices

    float* out       = (float*)d_out;
    float* out_area  = out;
    float* out_alpha = out + (size_t)T;
    unsigned int* vd = (unsigned int*)(out + 2 * (size_t)T);

    const int block = 256;
    int n4 = V / 4;

    size_t pairsB = (size_t)NB * BCAP * sizeof(uint2);   // 128 MB
    size_t cntB   = (size_t)NB * sizeof(unsigned);
    size_t v4B    = (size_t)V * sizeof(float4);          // 16 MB

    double mean = 4.0 * (double)T / NB;
    bool capOK = (mean + 12.0 * __builtin_sqrt(mean) <= (double)BCAP);
    bool fastOK = (V % 4 == 0) && (V <= (NB << VSHIFT)) && capOK && d_ws;

    int tetsPerBlock = block * RT * NR;   // 4096
    int nbAct = (V + (1 << VSHIFT) - 1) >> VSHIFT;

    if (fastOK && ws_size >= pairsB + cntB + v4B) {
        uint2*    pairs  = (uint2*)d_ws;
        unsigned* gcnt   = (unsigned*)((char*)d_ws + pairsB);
        float4*   verts4 = (float4*)((char*)d_ws + pairsB + ((cntB + 255) & ~(size_t)255));

        zero_kernel<<<(n4 + block - 1) / block, block, 0, stream>>>((uint4*)vd, n4, gcnt);
        pad_verts_kernel<<<(V + block - 1) / block, block, 0, stream>>>(verts, verts4, V);

        fused_geom_bin_kernel<<<(T + tetsPerBlock - 1) / tetsPerBlock, block, 0, stream>>>(
            verts4, (const int4*)indices, density, out_area, out_alpha, pairs, gcnt, vd, T);

        bucket_max_kernel<<<nbAct, 1024, 0, stream>>>(pairs, gcnt, vd, V);
    } else if (d_ws && ws_size >= v4B && (V % 4) == 0) {
        // tier-3: round-3 verified path
        zero_kernel<<<(n4 + block - 1) / block, block, 0, stream>>>((uint4*)vd, n4, nullptr);
        float4* verts4 = (float4*)d_ws;
        pad_verts_kernel<<<(V + block - 1) / block, block, 0, stream>>>(verts, verts4, V);
        tet_kernel_filter<<<(T + block - 1) / block, block, 0, stream>>>(
            verts4, indices, density, out_area, out_alpha, vd, T);
    } else {
        // tier-4: round-0 verified path
        zero_kernel<<<(n4 + block - 1) / block, block, 0, stream>>>((uint4*)vd, n4, nullptr);
        tet_kernel_fb<<<(T + block - 1) / block, block, 0, stream>>>(
            verts, (const int4*)indices, density, out_area, out_alpha, vd, T);
    }
}